// Round 12
// baseline (368.483 us; speedup 1.0000x reference)
//
#include <hip/hip_runtime.h>
#include <hip/hip_bf16.h>
#include <math.h>

#define B_ 8
#define N_ 1024
#define H_ 14
#define DH_ 64
#define D_ 896
#define M_ (B_*N_)        // 8192 rows
#define DQKV_ 2688        // 3*D_
#define TRBLK_ (14*14*4)  // transpose blocks
#define PPBLK_ (16*16)    // prep blocks

// exp2-domain constants: 2*log2(e), log2(e)*(1 - M0) with M0 = 12
#define TWO_LOG2E_ 2.8853900817779268f
#define BIAS_C_   (-15.869645449778597f)
#define QSCALE_     0.18033688011112043f   // 0.125 * log2(e), folded into Q at GEMM epilogue
#define RAD_        0.017453292519943295f

typedef __attribute__((ext_vector_type(8))) short bf16x8;
typedef __attribute__((ext_vector_type(4))) short bf16x4;
typedef __attribute__((ext_vector_type(4))) float f32x4;

__device__ __forceinline__ float bf2f(short s){
  unsigned u = ((unsigned)(unsigned short)s) << 16;
  union { unsigned u; float f; } c; c.u = u; return c.f;
}
__device__ __forceinline__ short f2bf(float f){
  union { float f; unsigned u; } c; c.f = f;
  unsigned u = c.u;
  unsigned r = (u + 0x7FFFu + ((u >> 16) & 1u)) >> 16;
  return (short)(unsigned short)r;
}
__device__ __forceinline__ float asf(unsigned u){
  union { unsigned u; float f; } c; c.u = u; return c.f;
}
// pack 2 f32 -> 2 bf16 in one VALU op (RNE -- bit-identical to f2bf above)
__device__ __forceinline__ unsigned cvt_pk_bf16(float lo, float hi){
  unsigned r;
  asm("v_cvt_pk_bf16_f32 %0, %1, %2" : "=v"(r) : "v"(lo), "v"(hi));
  return r;
}

// 16x16x16 bf16 MFMA: builtin when available, else ISA-verified inline asm.
#if __has_builtin(__builtin_amdgcn_mfma_f32_16x16x16bf16_1k)
#define MFMA16(D, A, B) (D) = __builtin_amdgcn_mfma_f32_16x16x16bf16_1k((A), (B), (D), 0, 0, 0)
#else
#define MFMA16(D, A, B) asm("v_mfma_f32_16x16x16_bf16 %0, %1, %2, %0" : "+v"(D) : "v"(A), "v"(B))
#endif

// raw workgroup barrier: LDS visibility only (lgkm), does NOT drain vmcnt ->
// global register-prefetches stay in flight across it.
#define BAR_LDS() do { asm volatile("s_waitcnt lgkmcnt(0)" ::: "memory"); \
                       __builtin_amdgcn_s_barrier(); } while (0)

// ---------------- fused pre-pass: LN + weight transpose + prep in ONE launch -------
// blockIdx ranges: [0, M_) = LayerNorm rows; [M_, M_+TRBLK_) = weight transpose;
// [M_+TRBLK_, +PPBLK_) = prep (csb OR alignQ+adjQ). All bodies verbatim from the
// r11 kernels; branch is block-uniform so __syncthreads inside is safe.
__global__ __launch_bounds__(256) void fused_pre(
    const float* __restrict__ x, const float* __restrict__ g,
    const float* __restrict__ bbv, short* __restrict__ y,
    const float* __restrict__ Wq, const float* __restrict__ Wk,
    const float* __restrict__ Wv, const float* __restrict__ Wo,
    short* __restrict__ WqkvT, short* __restrict__ WoT,
    const float* __restrict__ adj, const float* __restrict__ brg,
    const float* __restrict__ wdir,
    unsigned* __restrict__ csb, short* __restrict__ alignQ,
    short* __restrict__ adjQ, int do_align)
{
  __shared__ __align__(16) char smem_[20992];
  int bid = blockIdx.x;

  if (bid < M_){
    // ---- LayerNorm row ----
    float* rs_  = (float*)smem_;
    float* rs2_ = rs_ + 4;
    int row = bid;
    const float* xr = x + (size_t)row * D_;
    float s = 0.f, s2 = 0.f;
    for (int i = threadIdx.x; i < D_; i += 256){
      float v = xr[i]; s += v; s2 = fmaf(v, v, s2);
    }
    #pragma unroll
    for (int off = 32; off > 0; off >>= 1){
      s  += __shfl_down(s,  off, 64);
      s2 += __shfl_down(s2, off, 64);
    }
    int wv = threadIdx.x >> 6;
    if ((threadIdx.x & 63) == 0){ rs_[wv] = s; rs2_[wv] = s2; }
    __syncthreads();
    float ts  = rs_[0] + rs_[1] + rs_[2] + rs_[3];
    float ts2 = rs2_[0] + rs2_[1] + rs2_[2] + rs2_[3];
    float mu  = ts * (1.f / D_);
    float var = ts2 * (1.f / D_) - mu * mu;
    float rstd = rsqrtf(var + 1e-5f);
    short* yr = y + (size_t)row * D_;
    for (int i = threadIdx.x; i < D_; i += 256){
      yr[i] = f2bf((xr[i] - mu) * rstd * g[i] + bbv[i]);
    }
    return;
  }

  if (bid < M_ + TRBLK_){
    // ---- weight transpose ----
    short (*t)[72] = (short(*)[72])smem_;
    int rem = bid - M_;
    int z  = rem / 196;
    int r2 = rem - z * 196;
    int kb = (r2 % 14) * 64, nb = (r2 / 14) * 64;
    const float* W = (z == 0) ? Wq : (z == 1) ? Wk : (z == 2) ? Wv : Wo;
    int c0 = (threadIdx.x & 7) * 8;
    int r0 = threadIdx.x >> 3;            // 0..31
    #pragma unroll
    for (int rr = 0; rr < 64; rr += 32){
      const float* src = &W[(size_t)(kb + r0 + rr) * D_ + nb + c0];
      float4 a = *(const float4*)src;
      float4 b = *(const float4*)(src + 4);
      short* dstl = &t[r0 + rr][c0];
      dstl[0] = f2bf(a.x); dstl[1] = f2bf(a.y); dstl[2] = f2bf(a.z); dstl[3] = f2bf(a.w);
      dstl[4] = f2bf(b.x); dstl[5] = f2bf(b.y); dstl[6] = f2bf(b.z); dstl[7] = f2bf(b.w);
    }
    __syncthreads();
    short* dst = (z < 3) ? (WqkvT + (size_t)(z * D_) * D_) : WoT;
    #pragma unroll
    for (int rr = 0; rr < 64; rr += 32){
      int n = nb + r0 + rr;
      bf16x8 v;
      #pragma unroll
      for (int j = 0; j < 8; j++) v[j] = t[c0 + j][r0 + rr];
      *(bf16x8*)&dst[(size_t)n * D_ + kb + c0] = v;
    }
    return;
  }

  // ---- prep ----
  {
    float (*brgS)[65] = (float(*)[65])smem_;                     // 16640 B
    float (*cA_)[64]  = (float(*)[64])(smem_ + 16640);           // 2048 B
    float (*sA_)[64]  = (float(*)[64])(smem_ + 16640 + 2048);    // 2048 B
    int rem = bid - M_ - TRBLK_;
    int kt = rem & 15, qt = rem >> 4;
    int r  = threadIdx.x >> 2;          // 0..63
    int c0 = (threadIdx.x & 3) * 16;    // 0,16,32,48

    float bb16[16];
    {
      const float* bp = brg + (size_t)(kt * 64 + r) * N_ + qt * 64 + c0;
      #pragma unroll
      for (int i = 0; i < 16; i += 4){
        float4 bv = *(const float4*)(bp + i);
        bb16[i] = bv.x; bb16[i+1] = bv.y; bb16[i+2] = bv.z; bb16[i+3] = bv.w;
      }
    }

    if (do_align){
      #pragma unroll
      for (int i = 0; i < 16; i++) brgS[r][c0 + i] = bb16[i];
      for (int idx = threadIdx.x; idx < 512; idx += 256){
        int b = idx >> 6, qq = idx & 63;
        float A = wdir[(size_t)b * N_ + qt * 64 + qq] * RAD_;
        float s, c; __sincosf(A, &s, &c);
        sA_[b][qq] = s; cA_[b][qq] = c;
      }
      // adjQ[q][k] bf16 (coalesced read + write; numerics == r1-r4 bf16 adjT)
      {
        const float* ap = adj + (size_t)(qt * 64 + r) * N_ + kt * 64 + c0;
        unsigned w8[8];
        #pragma unroll
        for (int i = 0; i < 16; i += 4){
          float4 av = *(const float4*)(ap + i);
          w8[i/2]     = cvt_pk_bf16(av.x, av.y);
          w8[i/2 + 1] = cvt_pk_bf16(av.z, av.w);
        }
        short* dst = adjQ + (size_t)(qt * 64 + r) * N_ + kt * 64 + c0;
        *(uint4*)dst       = make_uint4(w8[0], w8[1], w8[2], w8[3]);
        *(uint4*)(dst + 8) = make_uint4(w8[4], w8[5], w8[6], w8[7]);
      }
      __syncthreads();
      // roles swap: r = q-local, c0 = k-local base
      float cB[16], sB[16];
      #pragma unroll
      for (int i = 0; i < 16; i++){
        float Br = (brgS[c0 + i][r] + 180.f) * RAD_;
        __sincosf(Br, &sB[i], &cB[i]);
      }
      #pragma unroll
      for (int b = 0; b < 8; b++){
        float ca = cA_[b][r], sa = sA_[b][r];
        unsigned w8[8];
        #pragma unroll
        for (int p = 0; p < 8; p++){
          float a0 = fmaf(ca, cB[2*p],     sa * sB[2*p]);
          float a1 = fmaf(ca, cB[2*p + 1], sa * sB[2*p + 1]);
          w8[p] = cvt_pk_bf16(a0, a1);
        }
        short* dst = alignQ + ((size_t)b * N_ + qt * 64 + r) * N_ + kt * 64 + c0;
        *(uint4*)dst       = make_uint4(w8[0], w8[1], w8[2], w8[3]);
        *(uint4*)(dst + 8) = make_uint4(w8[4], w8[5], w8[6], w8[7]);
      }
    } else {
      unsigned* cp = csb + (size_t)(kt * 64 + r) * N_ + qt * 64 + c0;
      #pragma unroll
      for (int i = 0; i < 16; i += 4){
        unsigned o[4];
        #pragma unroll
        for (int j = 0; j < 4; j++){
          float Br = (bb16[i + j] + 180.f) * RAD_;
          float sBv, cBv; __sincosf(Br, &sBv, &cBv);
          o[j] = ((unsigned)(unsigned short)f2bf(cBv)) |
                 (((unsigned)(unsigned short)f2bf(sBv)) << 16);
        }
        *(uint4*)(cp + i) = make_uint4(o[0], o[1], o[2], o[3]);
      }
    }
  }
}

// ---------------- MFMA GEMM: C[M x N] = A[M x K] * Bt[N x K]^T ----------------
// 1D grid + XCD-chunked bijective swizzle (nwg%8==0): each XCD owns a contiguous
// logical range = 8 m-tiles x all n-tiles -> its A-panel set (1.8 MB) is L2-resident
// across the n-sweep. rope path: RoPE+Q-scale; V-region tiles store direct to VT.
__global__ __launch_bounds__(256) void gemm_bt(const short* __restrict__ A,
                                               const short* __restrict__ Bt,
                                               short* __restrict__ C,
                                               float* __restrict__ Cf,
                                               const float* __restrict__ residf,
                                               short* __restrict__ VTo,
                                               int N, int rope)
{
  const int K = D_;
  __shared__ short As[128 * 32];
  __shared__ short Bs[128 * 32];
  int tid  = threadIdx.x;
  int wave = tid >> 6;
  int lane = tid & 63;
  int quad = lane >> 4;
  int l16  = lane & 15;
  int wr = wave >> 1, wc = wave & 1;

  // XCD swizzle: l2 = contiguous logical index per XCD; n fastest within logical.
  int nN    = N >> 7;
  int nwg   = (M_ >> 7) * nN;
  int chunk = nwg >> 3;
  int l     = blockIdx.x;
  int l2    = (l & 7) * chunk + (l >> 3);
  int mi    = l2 / nN;
  int ni    = l2 - mi * nN;
  int m0 = mi * 128;
  int n0 = ni * 128;

  f32x4 acc[4][4];
  #pragma unroll
  for (int i = 0; i < 4; i++)
    #pragma unroll
    for (int j = 0; j < 4; j++)
      acc[i][j] = (f32x4){0.f, 0.f, 0.f, 0.f};

  for (int k0 = 0; k0 < K; k0 += 32){
    __syncthreads();
    #pragma unroll
    for (int it = 0; it < 2; ++it){
      int c   = tid + it * 256;
      int row = c >> 2;
      int cc  = c & 3;
      const short* ga = A  + (size_t)(m0 + row) * K + k0 + cc * 8;
      const short* gb = Bt + (size_t)(n0 + row) * K + k0 + cc * 8;
      short* la = As + (size_t)(wave * 64 + it * 256) * 8;
      short* lb = Bs + (size_t)(wave * 64 + it * 256) * 8;
      __builtin_amdgcn_global_load_lds((const __attribute__((address_space(1))) void*)ga,
                                       (__attribute__((address_space(3))) void*)la, 16, 0, 0);
      __builtin_amdgcn_global_load_lds((const __attribute__((address_space(1))) void*)gb,
                                       (__attribute__((address_space(3))) void*)lb, 16, 0, 0);
    }
    __syncthreads();

    bf16x8 af[4], bfr[4];
    #pragma unroll
    for (int i = 0; i < 4; i++)
      af[i] = *(const bf16x8*)(As + (size_t)(wr * 64 + i * 16 + l16) * 32 + quad * 8);
    #pragma unroll
    for (int j = 0; j < 4; j++)
      bfr[j] = *(const bf16x8*)(Bs + (size_t)(wc * 64 + j * 16 + l16) * 32 + quad * 8);
    #pragma unroll
    for (int i = 0; i < 4; i++)
      #pragma unroll
      for (int j = 0; j < 4; j++)
        acc[i][j] = __builtin_amdgcn_mfma_f32_16x16x32_bf16(af[i], bfr[j], acc[i][j], 0, 0, 0);
  }

  int cb  = n0 + wc * 64;              // head base col (64-aligned)
  if (rope){
    int mat = cb / D_;                 // 0=Q, 1=K, 2=V
    if (mat < 2){
      float scale = (mat == 0) ? QSCALE_ : 1.0f;
      float invf0 = exp2f(-0.4152410118609203f * (float)l16);  // 10000^(-l16/32)
      float invf1 = invf0 * 0.01f;                             // 10000^(-(16+l16)/32)
      #pragma unroll
      for (int i = 0; i < 4; i++){
        #pragma unroll
        for (int rr = 0; rr < 4; rr++){
          int r = m0 + wr * 64 + i * 16 + quad * 4 + rr;
          float nseq = (float)(r & (N_ - 1));
          float s0, c0v, s1, c1v;
          __sincosf(nseq * invf0, &s0, &c0v);
          __sincosf(nseq * invf1, &s1, &c1v);
          float x1 = acc[i][0][rr], x2 = acc[i][2][rr];
          acc[i][0][rr] = (x1 * c0v - x2 * s0) * scale;
          acc[i][2][rr] = (x2 * c0v + x1 * s0) * scale;
          x1 = acc[i][1][rr]; x2 = acc[i][3][rr];
          acc[i][1][rr] = (x1 * c1v - x2 * s1) * scale;
          acc[i][3][rr] = (x2 * c1v + x1 * s1) * scale;
        }
      }
    }
  }

  if (rope && cb >= 2 * D_){
    // V tile -> VT[(b*H + h)*DH + d][tok], 4 tokens per 8B store (RNE like f2bf)
    int h   = (cb - 2 * D_) >> 6;
    int bb2 = m0 >> 10;                          // batch (128-row tile within one batch)
    int nb_ = (m0 & (N_ - 1)) + wr * 64 + quad * 4;
    #pragma unroll
    for (int i = 0; i < 4; i++){
      #pragma unroll
      for (int j = 0; j < 4; j++){
        int d = j * 16 + l16;
        short* vp = VTo + ((size_t)(bb2 * H_ + h) * DH_ + d) * N_ + nb_ + i * 16;
        unsigned o01 = cvt_pk_bf16(acc[i][j][0], acc[i][j][1]);
        unsigned o23 = cvt_pk_bf16(acc[i][j][2], acc[i][j][3]);
        *(uint2*)vp = make_uint2(o01, o23);
      }
    }
  } else {
    #pragma unroll
    for (int i = 0; i < 4; i++){
      #pragma unroll
      for (int rr = 0; rr < 4; rr++){
        int r = m0 + wr * 64 + i * 16 + quad * 4 + rr;
        size_t rowoff = (size_t)r * N;
        #pragma unroll
        for (int j = 0; j < 4; j++){
          int cidx = cb + j * 16 + l16;
          float v = acc[i][j][rr];
          if (Cf){
            Cf[rowoff + cidx] = v + residf[rowoff + cidx];
          } else {
            C[rowoff + cidx] = f2bf(v);
          }
        }
      }
    }
  }
}

// ---------------- Swapped-operand flash attention with LDS staging (r7 struct) ------
// Proven 142us config; only change this round: bias adj loads are bf16 (adjQ table,
// numerics validated r10) instead of f32 -> 4x8B instead of 4x16B per iter.
template<int PRE>
__global__ __launch_bounds__(256, 2) void attn_kernel(
    const short* __restrict__ QKV,
    const short* __restrict__ VT,       // [(b*H+h)*64 + d][tok] bf16
    const unsigned* __restrict__ csb,   // [k][q] packed (cosB, sinB)   (PRE=0)
    const float* __restrict__ adjF,     // [q][k] f32 (raw input)       (PRE=0)
    const short* __restrict__ alignQ,   // [b][q][k] bf16               (PRE=1)
    const short* __restrict__ adjQ,     // [q][k] bf16                  (PRE=1)
    const float* __restrict__ wind_dirs,
    const float* __restrict__ wind_w,
    const float* __restrict__ wind_b,
    short* __restrict__ outb)
{
  __shared__ short K_s[64 * 72];       // K[k][d]
  __shared__ short V_t[64 * 76];       // V^T[d][k]

  int bid = blockIdx.x;
  // bid = qt*112 + hh*8 + b  (112%8==0 -> XCD = bid%8 = b)
  int qt  = bid / 112;
  int rem = bid - qt * 112;
  int hh  = rem >> 3;
  int b   = rem & 7;
  int q0  = qt * 64;
  int kt0 = qt;                        // staggered start tile (order-invariant)

  int t    = threadIdx.x;
  int w    = t >> 6;          // 0..3
  int lane = t & 63;
  int quad = lane >> 4;
  int l16  = lane & 15;
  int q    = q0 + w * 16 + l16;        // this lane's q row

  // Q B-frags for x32 QK: B[n=q=l16][d = quad*8+j], halves d<32 / d>=32
  const short* qp = QKV + ((size_t)(b * N_) + q) * DQKV_ + hh * DH_ + quad * 8;
  bf16x8 qb0 = *(const bf16x8*)qp;
  bf16x8 qb1 = *(const bf16x8*)(qp + 32);

  float cAq = 0.f, sAq = 0.f;
  if (!PRE){
    float A = wind_dirs[(size_t)b * N_ + q] * RAD_;
    sAq = __sinf(A); cAq = __cosf(A);
  }
  float w0m = wind_w[hh]      * TWO_LOG2E_;
  float w1m = wind_w[H_ + hh] * TWO_LOG2E_;
  float wbm = wind_b[hh]      * TWO_LOG2E_;

  float lsum = 0.f;
  f32x4 OT[4];                         // OT[db]: O[d=db*16+quad*4+rr][q=l16]
  #pragma unroll
  for (int db = 0; db < 4; db++) OT[db] = (f32x4){0.f, 0.f, 0.f, 0.f};

  // staging: 4 threads/row, 2x16B each
  int sr = t >> 2, sc = (t & 3) * 16;
  const short* kg0 = QKV + ((size_t)(b * N_) + sr) * DQKV_ + D_ + hh * DH_ + sc;
  const short* vg0 = VT + ((size_t)(b * H_ + hh) * DH_ + sr) * N_ + sc;

  // per-lane bias row pointers ([q][k] layouts, k-contiguous)
  const short* al2 = alignQ + ((size_t)b * N_ + q) * N_ + quad * 4;
  const short* aj2 = adjQ + (size_t)q * N_ + quad * 4;
  const float* ad2 = adjF + (size_t)q * N_ + quad * 4;

  int k0f = kt0 * 64;
  // prologue prefetch (tile kt0): K/V staging registers
  bf16x8 pkA = *(const bf16x8*)(kg0 + (size_t)k0f * DQKV_);
  bf16x8 pkB = *(const bf16x8*)(kg0 + (size_t)k0f * DQKV_ + 8);
  bf16x8 pvA = *(const bf16x8*)(vg0 + k0f);
  bf16x8 pvB = *(const bf16x8*)(vg0 + k0f + 8);

  // prologue prefetch (tile kt0): bias inputs
  float4 ad4[4]; bf16x4 al4[4], aj4[4]; unsigned cs4[4][4];
  #pragma unroll
  for (int jc = 0; jc < 4; jc++){
    if (PRE){
      al4[jc] = *(const bf16x4*)(al2 + k0f + jc * 16);
      aj4[jc] = *(const bf16x4*)(aj2 + k0f + jc * 16);
    } else {
      ad4[jc] = *(const float4*)(ad2 + k0f + jc * 16);
      #pragma unroll
      for (int rr = 0; rr < 4; rr++)
        cs4[jc][rr] = csb[(size_t)(k0f + jc * 16 + quad * 4 + rr) * N_ + q];
    }
  }

  for (int it = 0; it < 16; ++it){
    int kn = (((it + 1 + kt0) & 15)) * 64;   // next tile base (wraps on last iter)

    BAR_LDS();                         // WAR: prev tile's LDS reads all consumed
    *(bf16x8*)(K_s + sr * 72 + sc)     = pkA;
    *(bf16x8*)(K_s + sr * 72 + sc + 8) = pkB;
    *(bf16x8*)(V_t + sr * 76 + sc)     = pvA;
    *(bf16x8*)(V_t + sr * 76 + sc + 8) = pvB;
    BAR_LDS();                         // RAW: staging visible; vmcnt NOT drained

    // issue next tile's K/V prefetch -- in flight under the whole compute phase
    pkA = *(const bf16x8*)(kg0 + (size_t)kn * DQKV_);
    pkB = *(const bf16x8*)(kg0 + (size_t)kn * DQKV_ + 8);
    pvA = *(const bf16x8*)(vg0 + kn);
    pvB = *(const bf16x8*)(vg0 + kn + 8);

    // S^T = K . Q^T  (lane: k = jc*16 + quad*4 + rr, q = l16)
    f32x4 S[4];
    __builtin_amdgcn_s_setprio(1);
    #pragma unroll
    for (int jc = 0; jc < 4; jc++){
      bf16x8 ka0 = *(const bf16x8*)(K_s + (jc * 16 + l16) * 72 + quad * 8);
      bf16x8 ka1 = *(const bf16x8*)(K_s + (jc * 16 + l16) * 72 + 32 + quad * 8);
      f32x4 s = (f32x4){0.f, 0.f, 0.f, 0.f};
      s = __builtin_amdgcn_mfma_f32_16x16x32_bf16(ka0, qb0, s, 0, 0, 0);
      s = __builtin_amdgcn_mfma_f32_16x16x32_bf16(ka1, qb1, s, 0, 0, 0);
      S[jc] = s;
    }
    __builtin_amdgcn_s_setprio(0);

    // per-jc: softmax (register P) -> PV MFMAs; bias prefetch after consumption
    #pragma unroll
    for (int jc = 0; jc < 4; jc++){
      float ev[4];
      #pragma unroll
      for (int rr = 0; rr < 4; rr++){
        float av, align;
        if (PRE){
          align = bf2f(al4[jc][rr]);
          av    = bf2f(aj4[jc][rr]);
        } else {
          float4 a4 = ad4[jc];
          av = (rr == 0) ? a4.x : (rr == 1) ? a4.y : (rr == 2) ? a4.z : a4.w;
          unsigned u = cs4[jc][rr];
          align = cAq * asf(u << 16) + sAq * asf(u & 0xffff0000u);
        }
        float z2 = fmaf(align, w0m, fmaf(av, w1m, wbm));    // 2*log2e*z
        float e2 = __builtin_amdgcn_exp2f(z2);              // e^{2z}
        float rc = __builtin_amdgcn_rcpf(e2 + 1.f);
        float bias2 = fmaf(-TWO_LOG2E_, rc, BIAS_C_);       // log2e*(tanh(z) - M0)
        float sv = (av > 0.f ? S[jc][rr] : -1e30f) + bias2;
        float e = __builtin_amdgcn_exp2f(sv);
        ev[rr] = e;
        lsum += e;
      }
      union { unsigned u2[2]; bf16x4 v4; } pu;
      pu.u2[0] = cvt_pk_bf16(ev[0], ev[1]);
      pu.u2[1] = cvt_pk_bf16(ev[2], ev[3]);
      bf16x4 pb = pu.v4;

      // prefetch next tile's bias inputs for this jc (consumed next iteration)
      if (PRE){
        al4[jc] = *(const bf16x4*)(al2 + kn + jc * 16);
        aj4[jc] = *(const bf16x4*)(aj2 + kn + jc * 16);
      } else {
        ad4[jc] = *(const float4*)(ad2 + kn + jc * 16);
        #pragma unroll
        for (int rr = 0; rr < 4; rr++)
          cs4[jc][rr] = csb[(size_t)(kn + jc * 16 + quad * 4 + rr) * N_ + q];
      }

      // PV: OT[db] += V^T . P^T, k-depth = jc*16 + quad*4 + j (P direct from regs)
      __builtin_amdgcn_s_setprio(1);
      #pragma unroll
      for (int db = 0; db < 4; db++){
        bf16x4 va = *(const bf16x4*)(V_t + (db * 16 + l16) * 76 + jc * 16 + quad * 4);
        MFMA16(OT[db], va, pb);
      }
      __builtin_amdgcn_s_setprio(0);
    }
  }

  // reduce lsum across the 4 quads (same q = l16), normalize, store O^T
  lsum += __shfl_xor(lsum, 16);
  lsum += __shfl_xor(lsum, 32);
  float rl = 1.f / lsum;

  short* op = outb + ((size_t)(b * N_) + q) * D_ + hh * DH_ + quad * 4;
  #pragma unroll
  for (int db = 0; db < 4; db++){
    unsigned o01 = cvt_pk_bf16(OT[db][0] * rl, OT[db][1] * rl);
    unsigned o23 = cvt_pk_bf16(OT[db][2] * rl, OT[db][3] * rl);
    *(uint2*)(op + db * 16) = make_uint2(o01, o23);
  }
}

extern "C" void kernel_launch(void* const* d_in, const int* in_sizes, int n_in,
                              void* d_out, int out_size, void* d_ws, size_t ws_size,
                              hipStream_t stream)
{
  const float* nf   = (const float*)d_in[0];
  const float* adj  = (const float*)d_in[1];
  const float* wdir = (const float*)d_in[2];
  const float* brg  = (const float*)d_in[3];
  const float* Wq   = (const float*)d_in[4];
  const float* Wk   = (const float*)d_in[5];
  const float* Wv   = (const float*)d_in[6];
  const float* Wo   = (const float*)d_in[7];
  const float* lng  = (const float*)d_in[8];
  const float* lnb  = (const float*)d_in[9];
  const float* ww   = (const float*)d_in[10];
  const float* wbb  = (const float*)d_in[11];
  float* out = (float*)d_out;

  short* base = (short*)d_ws;
  size_t sh = 0;
  short* xln   = base + sh;  sh += (size_t)M_ * D_;        // reused as attn out
  short* WqkvT = base + sh;  sh += (size_t)DQKV_ * D_;
  short* WoT   = base + sh;  sh += (size_t)D_ * D_;
  short* QKV   = base + sh;  sh += (size_t)M_ * DQKV_;
  short* VT    = base + sh;  sh += (size_t)B_ * H_ * DH_ * N_;       // 14.7 MB
  unsigned* csb = (unsigned*)(base + sh); sh += (size_t)N_ * N_ * 2; // u32 = 2 shorts
  short* alignQ = base + sh; sh += (size_t)B_ * N_ * N_;   // optional (pre)
  short* adjQ   = base + sh; sh += (size_t)N_ * N_;        // optional (pre)
  size_t need_pre = sh * sizeof(short);
  bool pre = (ws_size >= need_pre);

  fused_pre<<<M_ + TRBLK_ + PPBLK_, 256, 0, stream>>>(
      nf, lng, lnb, xln, Wq, Wk, Wv, Wo, WqkvT, WoT,
      adj, brg, wdir, csb, alignQ, adjQ, pre ? 1 : 0);
  gemm_bt<<<(M_ / 128) * (DQKV_ / 128), 256, 0, stream>>>(
      xln, WqkvT, QKV, nullptr, nullptr, VT, DQKV_, 1);
  if (pre)
    attn_kernel<1><<<B_ * H_ * 16, 256, 0, stream>>>(QKV, VT, csb, adj, alignQ, adjQ, wdir, ww, wbb, xln);
  else
    attn_kernel<0><<<B_ * H_ * 16, 256, 0, stream>>>(QKV, VT, csb, adj, alignQ, adjQ, wdir, ww, wbb, xln);
  gemm_bt<<<(M_ / 128) * (D_ / 128), 256, 0, stream>>>(
      xln, WoT, nullptr, out, nf, nullptr, D_, 0);
}